// Round 9
// baseline (238.172 us; speedup 1.0000x reference)
//
#include <hip/hip_runtime.h>

constexpr int kNR = 40000;
constexpr int kNU = 30000;
constexpr int kNP = 30000;
constexpr int kN  = 100000;          // total nodes
constexpr int kE  = 1600000;         // edges
constexpr int kF  = 128;             // feature/hidden dim
constexpr int kC  = 40;              // classes
constexpr int kBN = 64;              // nodes per bucket (mega block)
constexpr int kNB = (kN + kBN - 1) / kBN;   // 1563 buckets
constexpr int kNBp = 1600;           // padded bucket-count stride
constexpr int kSlot = 2048;          // fixed slot capacity per bucket (avg 1024)
// merged prep kernel geometry (1024 threads per block)
constexpr int kPackB = 98;           // pack blocks: 98*1024 >= kN
constexpr int kFuseB = kPackB;       // block 98: fuse weights
constexpr int kW2B   = kPackB + 1;   // block 99: w2frag
constexpr int kScat0 = kPackB + 2;   // blocks 100..355: scatter
constexpr int kScatB = 256;          // scatter blocks
constexpr int kCE    = kE / kScatB;  // 6250 edges per scatter block
constexpr int kEPT   = (kCE + 1023) / 1024;   // 7 edges per thread (register carry)
constexpr int kPrepB = kScat0 + kScatB;   // 356 blocks
// layer-2 plane partition v2: 4 planes x 10 classes, rows PACKED 20B (5 uints);
// per-plane table = 2 MB -> L2-resident on its XCD. XCD x (= blockIdx%8 under
// round-robin) serves plane x%4, node-half x>=4. Gather outputs go to plane-major
// f32 regions (no cross-XCD false sharing); a tiny merge kernel relayouts.
constexpr int kPl  = 4;              // planes
constexpr int kPC  = 10;             // classes per plane
constexpr int kGK  = 12500;          // k range per (plane,half): 12500*2*4 = 100000 = kN
constexpr int kGatB = 8 * kGK;       // 100000 gather blocks (4 nodes each)

typedef __attribute__((ext_vector_type(8))) short bf16x8;   // MFMA A/B frag
typedef __attribute__((ext_vector_type(4))) float f32x4;    // MFMA C/D frag

// ---------- bf16 helpers ----------
__device__ __forceinline__ float bf_to_f(unsigned short h) {
    union { unsigned int i; float f; } u; u.i = ((unsigned int)h) << 16; return u.f;
}
__device__ __forceinline__ unsigned short f_to_bf(float f) {
    union { unsigned int i; float f; } u; u.f = f;
    unsigned int r = u.i + 0x7FFFu + ((u.i >> 16) & 1u);   // RNE
    return (unsigned short)(r >> 16);
}
__device__ __forceinline__ float2 bf2_to_f2(unsigned int p) {
    union { unsigned int i; float f; } lo, hi;
    lo.i = (p & 0xFFFFu) << 16;
    hi.i = p & 0xFFFF0000u;
    return make_float2(lo.f, hi.f);
}
__device__ __forceinline__ unsigned int pack_bf2(float a, float b) {
    return (unsigned int)f_to_bf(a) | ((unsigned int)f_to_bf(b) << 16);
}
__device__ __forceinline__ float ldf(const void* p, int i, int isbf) {
    return isbf ? bf_to_f(((const unsigned short*)p)[i]) : ((const float*)p)[i];
}
__device__ __forceinline__ int lde(const int* p, int i, int is64) {
    return is64 ? p[2 * i] : p[i];
}

// in-kernel dtype sniff: wave 0 ballots, result broadcast via LDS.
__device__ __forceinline__ int sniff_isbf(const void* W1, int t, int* sh) {
    if (t < 64) {
        unsigned int wv = ((const unsigned int*)W1)[t];
        unsigned int ax = wv & 0x7FFFu;
        int pl = (ax == 0u) || (ax > 0x2000u && ax < 0x4000u);
        unsigned long long mk = __ballot(pl);
        if (t == 0) *sh = (__popcll(mk) >= 48) ? 1 : 0;
    }
    __syncthreads();
    return *sh;
}

// ---------- MERGED prep: pack | fuse | w2frag | fused count+reserve+scatter ----------
// gcnt pre-zeroed by hipMemsetAsync. Scatter carries edge rows in registers across the
// hist -> reserve -> scatter phases: ei is read exactly once.
__global__ void __launch_bounds__(1024) gcn_prep(
        const void* __restrict__ xr, const void* __restrict__ xu, const void* __restrict__ xp,
        const void* __restrict__ Wr, const void* __restrict__ br,
        const void* __restrict__ Wu, const void* __restrict__ bu,
        const void* __restrict__ Wp, const void* __restrict__ bp,
        const void* __restrict__ W1, const void* __restrict__ W2,
        const int* __restrict__ ei,
        unsigned short* __restrict__ fwfrag, unsigned short* __restrict__ w2frag,
        uint4* __restrict__ xpack, int* __restrict__ gcnt,
        unsigned int* __restrict__ slots) {
    __shared__ __align__(16) char smem[29696];
    __shared__ int sflag;
    int t = threadIdx.x;
    int bx = blockIdx.x;
    if (bx < kPackB) {                       // ---- pack (1024 thr) ----
        int isbf = sniff_isbf(W1, t, &sflag);
        int n = bx * 1024 + t;
        if (n >= kN) return;
        const void* base; int roff, d;
        if (n < kNR)            { base = xr; roff = n * 5;               d = 5; }
        else if (n < kNR + kNU) { base = xu; roff = (n - kNR) * 7;       d = 7; }
        else                    { base = xp; roff = (n - kNR - kNU) * 6; d = 6; }
        float f[8];
        #pragma unroll
        for (int i = 0; i < 8; i++) f[i] = (i < d) ? ldf(base, roff + i, isbf) : 0.f;
        uint4 u;
        u.x = pack_bf2(f[0], f[1]);  u.y = pack_bf2(f[2], f[3]);
        u.z = pack_bf2(f[4], f[5]);  u.w = pack_bf2(f[6], f[7]);
        xpack[n] = u;
    } else if (bx == kFuseB) {               // ---- fuse -> fwfrag (split-k, 256 active) ----
        int isbf = sniff_isbf(W1, t, &sflag);
        float* sw   = (float*)smem;                          // 21*128 f32 = 10752 B
        float* pacc = (float*)(smem + 10752);                // 10752 B
        unsigned short* flds = (unsigned short*)(smem + 21504);  // 8192 B
        for (int i = t; i < 21 * kF; i += 1024) {
            int r = i >> 7, c = i & 127;
            float v;
            if (r < 5)        v = ldf(Wr, r * kF + c, isbf);
            else if (r < 12)  v = ldf(Wu, (r - 5) * kF + c, isbf);
            else if (r < 18)  v = ldf(Wp, (r - 12) * kF + c, isbf);
            else if (r == 18) v = ldf(br, c, isbf);
            else if (r == 19) v = ldf(bu, c, isbf);
            else              v = ldf(bp, c, isbf);
            sw[i] = v;
        }
        __syncthreads();
        {
            bool active = (t < 256);
            int j = t & 127, half = (t >> 7) & 1;
            float acc[21];
            #pragma unroll
            for (int r = 0; r < 21; r++) acc[r] = 0.f;
            if (active) {
                int k0 = half * 64, k1 = k0 + 64;
                for (int k = k0; k < k1; k++) {
                    float w1 = ldf(W1, k * kF + j, isbf);
                    #pragma unroll
                    for (int r = 0; r < 21; r++) acc[r] += sw[r * kF + k] * w1;
                }
            }
            if (active && half == 1) {
                #pragma unroll
                for (int r = 0; r < 21; r++) pacc[r * kF + j] = acc[r];
            }
            __syncthreads();
            if (active && half == 0) {
                #pragma unroll
                for (int r = 0; r < 21; r++) acc[r] += pacc[r * kF + j];
                unsigned short row[32];
                #pragma unroll
                for (int s = 0; s < 32; s++) row[s] = 0;
                #pragma unroll
                for (int i = 0; i < 5; i++) row[0  + i] = f_to_bf(acc[i]);
                #pragma unroll
                for (int i = 0; i < 7; i++) row[8  + i] = f_to_bf(acc[5 + i]);
                #pragma unroll
                for (int i = 0; i < 6; i++) row[16 + i] = f_to_bf(acc[12 + i]);
                row[24] = f_to_bf(acc[18]);  row[25] = f_to_bf(acc[19]);  row[26] = f_to_bf(acc[20]);
                #pragma unroll
                for (int s = 0; s < 32; s++) flds[j * 32 + s] = row[s];
            }
        }
        __syncthreads();
        for (int idx = t; idx < 8 * 64; idx += 1024) {
            int t8 = idx >> 6, lane = idx & 63;
            int mm = lane & 15, q = lane >> 4;
            #pragma unroll
            for (int j = 0; j < 8; j++)
                fwfrag[idx * 8 + j] = flds[(16 * t8 + mm) * 32 + q * 8 + j];
        }
    } else if (bx == kW2B) {                 // ---- W2 -> w2frag ----
        int isbf = sniff_isbf(W1, t, &sflag);
        for (int idx = t; idx < 12 * 64; idx += 1024) {
            int st = idx >> 6, lane = idx & 63;
            int s = st / 3, tt = st % 3;
            int mm = lane & 15, q = lane >> 4;
            int cls = 16 * tt + mm;
            #pragma unroll
            for (int j = 0; j < 8; j++) {
                int k = s * 32 + q * 8 + j;
                w2frag[idx * 8 + j] = (cls < kC) ? f_to_bf(ldf(W2, k * kC + cls, isbf))
                                                 : (unsigned short)0;
            }
        }
    } else {                                 // ---- scatter (256 blocks x 6250 edges) ----
        int* hist = (int*)smem;              // 6400 B
        int* cur  = (int*)(smem + 6400);     // 6400 B
        if (t < 64) {
            int v = ((const int*)ei)[2 * t + 1];
            unsigned long long mk = __ballot(v != 0);
            if (t == 0) sflag = (mk == 0ull) ? 1 : 0;
        }
        for (int i = t; i < kNBp; i += 1024) hist[i] = 0;
        __syncthreads();
        int is64 = sflag;
        int blk = bx - kScat0;
        int e0 = blk * kCE, e1 = e0 + kCE;
        // single read of both edge rows -> registers
        unsigned int dv[kEPT], sv[kEPT];
        #pragma unroll
        for (int it = 0; it < kEPT; it++) {
            int e = e0 + t + it * 1024;
            bool ok = (e < e1);
            dv[it] = ok ? (unsigned int)lde(ei, kE + e, is64) : 0xFFFFFFFFu;
            sv[it] = ok ? (unsigned int)lde(ei, e, is64) : 0u;
        }
        // pass 1: per-bucket histogram
        #pragma unroll
        for (int it = 0; it < kEPT; it++)
            if (dv[it] < (unsigned int)kN) atomicAdd(&hist[dv[it] >> 6], 1);
        __syncthreads();
        // pass 2: reserve ranges (rotated start to spread same-address contention)
        int off = (blk * 401) % kNBp;
        for (int j = t; j < kNBp; j += 1024) {
            int i = j + off;
            if (i >= kNBp) i -= kNBp;
            int h = hist[i];
            cur[i] = (h > 0) ? atomicAdd(&gcnt[i], h) : 0;
        }
        __syncthreads();
        // pass 3: scatter pairs from registers
        #pragma unroll
        for (int it = 0; it < kEPT; it++) {
            if (dv[it] < (unsigned int)kN) {
                unsigned int sval = (sv[it] < (unsigned int)kN) ? sv[it] : 0u;
                int b = (int)(dv[it] >> 6);
                int pos = atomicAdd(&cur[b], 1);
                if (pos < kSlot) slots[(size_t)b * kSlot + pos] = (sval << 6) | (dv[it] & 63u);
            }
        }
    }
}

// ---------- MEGA bucket kernel (256 thr): CSR build + layer-1 agg (4 lanes/node) + MFMA ----------
__global__ void __launch_bounds__(256) GCN_2190433321521_kernel(
        const unsigned int* __restrict__ slots,
        const int* __restrict__ gcnt,
        const uint4* __restrict__ xpack,
        const unsigned short* __restrict__ fwfrag,
        const unsigned short* __restrict__ w2frag,
        int* __restrict__ rpb,
        int* __restrict__ rpe,
        int* __restrict__ col,
        unsigned int* __restrict__ hpl) {
    __shared__ __align__(16) char smem[25600];
    float*          agg_l  = (float*)smem;                       // [64][29] fp32, 7424 B
    int*            cnt_l  = (int*)(smem + 7424);                // [64] working cursors
    int*            strt_l = (int*)(smem + 7680);                // [64] start cursors
    int*            cntv_l = (int*)(smem + 7936);                // [64] node counts
    unsigned int*   wst    = (unsigned int*)(smem + 8192);       // pair stash [2048], 8 KB
    int*            col_l  = (int*)(smem + 16384);               // col staging [2048], 8 KB
    unsigned short* hbuf   = (unsigned short*)(smem + 8192);     // [4][16][136] (aliases wst+col_l)
    unsigned short* cst    = (unsigned short*)smem;              // c2 stage [64][40] (aliases agg_l)

    int b = blockIdx.x;
    int base = b * kBN;
    int nn = min(kBN, kN - base);
    int tid = threadIdx.x;

    if (tid < kBN) cnt_l[tid] = 0;
    __syncthreads();
    int p0 = b * kSlot;
    int m = min(gcnt[b], kSlot);
    int p1 = p0 + m;

    // pass 1: load pairs once -> stash + per-node histogram
    for (int ib = p0 + tid; ib < p1; ib += 1024) {
        unsigned int w[4]; int ok[4];
        #pragma unroll
        for (int j = 0; j < 4; j++) {
            int i = ib + j * 256;
            ok[j] = (i < p1);
            w[j] = ok[j] ? slots[i] : 0u;
        }
        #pragma unroll
        for (int j = 0; j < 4; j++) {
            int i = ib + j * 256;
            if (ok[j]) {
                wst[i - p0] = w[j];
                atomicAdd(&cnt_l[w[j] & 63u], 1);
            }
        }
    }
    __syncthreads();
    // wave-0 shfl scan over the 64 node-counts
    if (tid < 64) {
        int v = cnt_l[tid];
        int incl = v;
        #pragma unroll
        for (int o = 1; o < 64; o <<= 1) {
            int y = __shfl_up(incl, o, 64);
            if (tid >= o) incl += y;
        }
        int cursor = p0 + incl - v;
        cnt_l[tid]  = cursor;
        strt_l[tid] = cursor;
        cntv_l[tid] = v;
        if (tid < nn) { rpb[base + tid] = cursor; rpe[base + tid] = cursor + v; }
    }
    __syncthreads();

    // pass 2a: col build only (1 LDS atomic per edge)
    for (int i = p0 + tid; i < p1; i += 256) {
        unsigned int w = wst[i - p0];
        unsigned int s = w >> 6;
        int dloc = (int)(w & 63u);
        int pos = atomicAdd(&cnt_l[dloc], 1);
        col_l[pos - p0] = (int)s;
    }
    __syncthreads();
    for (int i = tid; i < m; i += 256) col[p0 + i] = col_l[i];

    // pass 2b: 4 threads per node; register accumulation of 27 slots
    {
        int node = tid >> 2, j = tid & 3;
        float aR[8], aU[8], aP[8];
        #pragma unroll
        for (int i = 0; i < 8; i++) { aR[i] = 0.f; aU[i] = 0.f; aP[i] = 0.f; }
        float cR = 0.f, cU = 0.f, cP = 0.f;
        int start = strt_l[node] - p0;
        int c = cntv_l[node];
        for (int i = start + j; i < start + c; i += 4) {
            int s = col_l[i];
            uint4 u = xpack[s];
            float2 q0 = bf2_to_f2(u.x), q1 = bf2_to_f2(u.y);
            float2 q2 = bf2_to_f2(u.z), q3 = bf2_to_f2(u.w);
            if (s < kNR) {
                aR[0]+=q0.x; aR[1]+=q0.y; aR[2]+=q1.x; aR[3]+=q1.y;
                aR[4]+=q2.x; aR[5]+=q2.y; aR[6]+=q3.x; aR[7]+=q3.y; cR += 1.f;
            } else if (s < kNR + kNU) {
                aU[0]+=q0.x; aU[1]+=q0.y; aU[2]+=q1.x; aU[3]+=q1.y;
                aU[4]+=q2.x; aU[5]+=q2.y; aU[6]+=q3.x; aU[7]+=q3.y; cU += 1.f;
            } else {
                aP[0]+=q0.x; aP[1]+=q0.y; aP[2]+=q1.x; aP[3]+=q1.y;
                aP[4]+=q2.x; aP[5]+=q2.y; aP[6]+=q3.x; aP[7]+=q3.y; cP += 1.f;
            }
        }
        #pragma unroll
        for (int i2 = 0; i2 < 8; i2++) {
            float v = aR[i2];
            v += __shfl_xor(v, 1, 64);  v += __shfl_xor(v, 2, 64);
            if (j == 0) agg_l[node * 29 + i2] = v;
        }
        #pragma unroll
        for (int i2 = 0; i2 < 8; i2++) {
            float v = aU[i2];
            v += __shfl_xor(v, 1, 64);  v += __shfl_xor(v, 2, 64);
            if (j == 0) agg_l[node * 29 + 8 + i2] = v;
        }
        #pragma unroll
        for (int i2 = 0; i2 < 8; i2++) {
            float v = aP[i2];
            v += __shfl_xor(v, 1, 64);  v += __shfl_xor(v, 2, 64);
            if (j == 0) agg_l[node * 29 + 16 + i2] = v;
        }
        float v = cR;
        v += __shfl_xor(v, 1, 64);  v += __shfl_xor(v, 2, 64);
        if (j == 0) agg_l[node * 29 + 24] = v;
        v = cU;
        v += __shfl_xor(v, 1, 64);  v += __shfl_xor(v, 2, 64);
        if (j == 0) agg_l[node * 29 + 25] = v;
        v = cP;
        v += __shfl_xor(v, 1, 64);  v += __shfl_xor(v, 2, 64);
        if (j == 0) agg_l[node * 29 + 26] = v;
    }
    __syncthreads();   // agg_l complete; wst/col_l dead -> hbuf region live

    // ---- fused dense (MFMA): each wave = one 16-node tile; B-frags from global ----
    int wid = tid >> 6, lane = tid & 63;
    int mm = lane & 15, q = lane >> 4;
    int node = wid * 16 + mm;
    bf16x8 a1;
    #pragma unroll
    for (int j = 0; j < 8; j++) {
        int sl = q * 8 + j;
        a1[j] = (sl < 27) ? (short)f_to_bf(agg_l[node * 29 + sl]) : (short)0;
    }
    __syncthreads();   // agg_l fully consumed; cst (aliasing it) may now be written
    const bf16x8* fwf = (const bf16x8*)fwfrag;
    f32x4 c1[8];
    #pragma unroll
    for (int t = 0; t < 8; t++) {
        f32x4 z = {0.f, 0.f, 0.f, 0.f};
        c1[t] = __builtin_amdgcn_mfma_f32_16x16x32_bf16(a1, fwf[t * 64 + lane], z, 0, 0, 0);
    }
    unsigned short* hb = hbuf + wid * 16 * 136;
    #pragma unroll
    for (int t = 0; t < 8; t++) {
        #pragma unroll
        for (int r = 0; r < 4; r++)
            hb[(q * 4 + r) * 136 + 16 * t + mm] = f_to_bf(fmaxf(c1[t][r], 0.f));
    }
    const bf16x8* w2f = (const bf16x8*)w2frag;
    f32x4 c2[3];
    #pragma unroll
    for (int t = 0; t < 3; t++) { c2[t].x = 0.f; c2[t].y = 0.f; c2[t].z = 0.f; c2[t].w = 0.f; }
    #pragma unroll
    for (int s = 0; s < 4; s++) {
        bf16x8 a2 = *(const bf16x8*)&hb[mm * 136 + s * 32 + q * 8];
        #pragma unroll
        for (int t = 0; t < 3; t++)
            c2[t] = __builtin_amdgcn_mfma_f32_16x16x32_bf16(a2, w2f[(s * 3 + t) * 64 + lane],
                                                            c2[t], 0, 0, 0);
    }
    // stage c2 into LDS, then write 4 packed class-plane tables (20B rows, coalesced)
    #pragma unroll
    for (int t = 0; t < 3; t++) {
        int cls = 16 * t + mm;
        if (cls < kC) {
            #pragma unroll
            for (int r = 0; r < 4; r++)
                cst[(wid * 16 + q * 4 + r) * kC + cls] = f_to_bf(c2[t][r]);
        }
    }
    __syncthreads();
    {
        const unsigned int* cs32 = (const unsigned int*)cst;   // [64][20] uints
        #pragma unroll
        for (int p = 0; p < kPl; p++) {
            for (int i = tid; i < nn * 5; i += 256) {
                int row = i / 5, cp = i % 5;
                hpl[(size_t)p * kN * 5 + (size_t)(base + row) * 5 + cp]
                    = cs32[row * 20 + p * 5 + cp];
            }
        }
    }
}

// ---------- layer-2 gather: plane-partitioned, XCD-pinned, wave-per-node ----------
// XCD x = blockIdx%8 serves plane x%4, node-half x>=4: random gathers hit a 2 MB
// L2-resident table. Outputs to plane-major f32 regions (no cross-XCD sharing).
// 12 groups x 5 lanes per wave: 24 edges in flight per node.
__global__ void __launch_bounds__(256) gcn_gather2(const unsigned int* __restrict__ hpl,
                                                   const int* __restrict__ rpb,
                                                   const int* __restrict__ rpe,
                                                   const int* __restrict__ col,
                                                   float* __restrict__ op) {
    int bid = blockIdx.x;
    int r = bid & 7;
    int plane = r & 3;
    int half = r >> 2;
    int k = bid >> 3;                       // 0..12499
    int t = threadIdx.x;
    int wid = t >> 6, lane = t & 63;
    int n = (half * kGK + k) * 4 + wid;     // exact cover of [0, kN)
    const unsigned int* hp = hpl + (size_t)plane * kN * 5;
    int grp = lane / 5;                     // 0..11 active (60 lanes), 60-63 idle
    int cp  = lane % 5;
    int beg = rpb[n], end = rpe[n];
    float f0 = 0.f, f1 = 0.f;
    if (grp < 12) {
        int e = beg + grp;
        int c0 = (e      < end) ? col[e]      : -1;
        int c1 = (e + 12 < end) ? col[e + 12] : -1;
        if (c0 >= 0) { float2 a = bf2_to_f2(hp[(size_t)c0 * 5 + cp]); f0 += a.x; f1 += a.y; }
        if (c1 >= 0) { float2 a = bf2_to_f2(hp[(size_t)c1 * 5 + cp]); f0 += a.x; f1 += a.y; }
        for (e += 24; e < end; e += 12) {   // rare tail (degree > 24)
            float2 a = bf2_to_f2(hp[(size_t)col[e] * 5 + cp]);
            f0 += a.x; f1 += a.y;
        }
    }
    // fold 12 groups -> group 0 (lanes 0..4)
    f0 += __shfl(f0, lane + 30, 64);  f1 += __shfl(f1, lane + 30, 64);
    f0 += __shfl(f0, lane + 15, 64);  f1 += __shfl(f1, lane + 15, 64);
    f0 += __shfl(f0, lane + 5, 64) + __shfl(f0, lane + 10, 64);
    f1 += __shfl(f1, lane + 5, 64) + __shfl(f1, lane + 10, 64);
    if (lane < 5) {
        float* o = op + ((size_t)plane * kN + n) * kPC;
        o[2 * cp]     = f0;
        o[2 * cp + 1] = f1;
    }
}

// ---------- merge: relayout plane-major f32 partials into the output ----------
__global__ void __launch_bounds__(256) gcn_merge(const float* __restrict__ op,
                                                 unsigned int* __restrict__ out,
                                                 const void* __restrict__ W1) {
    __shared__ int sisbf;
    int t = threadIdx.x;
    int isbf = sniff_isbf(W1, t, &sisbf);
    int n = blockIdx.x * 256 + t;
    if (n >= kN) return;
    if (isbf) {
        #pragma unroll
        for (int p = 0; p < kPl; p++) {
            const float* src = op + ((size_t)p * kN + n) * kPC;
            #pragma unroll
            for (int c = 0; c < 5; c++)
                out[n * 20 + p * 5 + c] = pack_bf2(src[2 * c], src[2 * c + 1]);
        }
    } else {
        float* of = (float*)out;
        #pragma unroll
        for (int p = 0; p < kPl; p++) {
            const float* src = op + ((size_t)p * kN + n) * kPC;
            #pragma unroll
            for (int c = 0; c < kPC; c++)
                of[n * kC + p * kPC + c] = src[c];
        }
    }
}

extern "C" void kernel_launch(void* const* d_in, const int* in_sizes, int n_in,
                              void* d_out, int out_size, void* d_ws, size_t ws_size,
                              hipStream_t stream) {
    const void* xr = d_in[0];
    const void* xu = d_in[1];
    const void* xp = d_in[2];
    const int*  ei = (const int*)d_in[3];
    const void* Wr = d_in[4];
    const void* br = d_in[5];
    const void* Wu = d_in[6];
    const void* bu = d_in[7];
    const void* Wp = d_in[8];
    const void* bp = d_in[9];
    const void* W1 = d_in[10];
    const void* W2 = d_in[11];
    (void)in_sizes; (void)n_in; (void)out_size; (void)ws_size;

    char* ws = (char*)d_ws;
    size_t off = 0;
    auto alloc = [&](size_t bytes) -> void* {
        void* p = (void*)(ws + off);
        off = (off + bytes + 255) & ~(size_t)255;
        return p;
    };
    int*            gcnt   = (int*)           alloc((size_t)kNBp * 4);           // 6.4 KB
    unsigned short* fwfrag = (unsigned short*)alloc(8 * 64 * 8 * 2);             // 8 KB
    unsigned short* w2frag = (unsigned short*)alloc(12 * 64 * 8 * 2);            // 12 KB
    uint4*          xpack  = (uint4*)         alloc((size_t)kN * 16);            // 1.6 MB
    unsigned int*   slots  = (unsigned int*)  alloc((size_t)kNB * kSlot * 4);    // 12.8 MB
    int*            col    = (int*)           alloc((size_t)kNB * kSlot * 4);    // 12.8 MB
    int*            rpb    = (int*)           alloc((size_t)kN * 4);             // 0.4 MB
    int*            rpe    = (int*)           alloc((size_t)kN * 4);             // 0.4 MB
    unsigned int*   hpl    = (unsigned int*)  alloc((size_t)kPl * kN * 5 * 4);   // 8 MB
    float*          op     = (float*)         alloc((size_t)kPl * kN * kPC * 4); // 16 MB

    hipMemsetAsync(gcnt, 0, (size_t)kNBp * 4, stream);
    gcn_prep<<<kPrepB, 1024, 0, stream>>>(xr, xu, xp, Wr, br, Wu, bu, Wp, bp, W1, W2,
                                          ei, fwfrag, w2frag, xpack, gcnt, slots);
    GCN_2190433321521_kernel<<<kNB, 256, 0, stream>>>(slots, gcnt, xpack, fwfrag, w2frag,
                                                      rpb, rpe, col, hpl);
    gcn_gather2<<<kGatB, 256, 0, stream>>>(hpl, rpb, rpe, col, op);
    gcn_merge<<<(kN + 255) / 256, 256, 0, stream>>>(op, (unsigned int*)d_out, W1);
}

// Round 10
// 173.577 us; speedup vs baseline: 1.3721x; 1.3721x over previous
//
#include <hip/hip_runtime.h>

constexpr int kNR = 40000;
constexpr int kNU = 30000;
constexpr int kNP = 30000;
constexpr int kN  = 100000;          // total nodes
constexpr int kE  = 1600000;         // edges
constexpr int kF  = 128;             // feature/hidden dim
constexpr int kC  = 40;              // classes
constexpr int kHS = 64;              // hw row stride in shorts (128 B, line-aligned)
constexpr int kBN = 64;              // nodes per bucket (mega block)
constexpr int kNB = (kN + kBN - 1) / kBN;   // 1563 buckets
constexpr int kNBp = 1600;           // padded bucket-count stride
constexpr int kSlot = 2048;          // fixed slot capacity per bucket (avg 1024)
// merged prep kernel geometry (1024 threads per block)
constexpr int kPackB = 98;           // pack blocks: 98*1024 >= kN
constexpr int kFuseB = kPackB;       // block 98: fuse weights
constexpr int kW2B   = kPackB + 1;   // block 99: w2frag
constexpr int kScat0 = kPackB + 2;   // blocks 100..227: scatter
constexpr int kScatB = 128;          // scatter blocks (fewer -> longer slot runs, less write amp)
constexpr int kCE    = kE / kScatB;  // 12500 edges per scatter block
constexpr int kEPT   = (kCE + 1023) / 1024;   // 13 edges per thread (register carry)
constexpr int kPrepB = kScat0 + kScatB;   // 228 blocks
// gather2 geometry: 25000 blocks x 256 thr (4 nodes/block); bijective XCD-chunk swizzle
constexpr int kGB2 = (kN * 64) / 256;     // 25000
constexpr int kGQ  = kGB2 / 8;            // 3125 (exact)

typedef __attribute__((ext_vector_type(8))) short bf16x8;   // MFMA A/B frag
typedef __attribute__((ext_vector_type(4))) float f32x4;    // MFMA C/D frag

// ---------- bf16 helpers ----------
__device__ __forceinline__ float bf_to_f(unsigned short h) {
    union { unsigned int i; float f; } u; u.i = ((unsigned int)h) << 16; return u.f;
}
__device__ __forceinline__ unsigned short f_to_bf(float f) {
    union { unsigned int i; float f; } u; u.f = f;
    unsigned int r = u.i + 0x7FFFu + ((u.i >> 16) & 1u);   // RNE
    return (unsigned short)(r >> 16);
}
__device__ __forceinline__ float2 bf2_to_f2(unsigned int p) {
    union { unsigned int i; float f; } lo, hi;
    lo.i = (p & 0xFFFFu) << 16;
    hi.i = p & 0xFFFF0000u;
    return make_float2(lo.f, hi.f);
}
__device__ __forceinline__ unsigned int pack_bf2(float a, float b) {
    return (unsigned int)f_to_bf(a) | ((unsigned int)f_to_bf(b) << 16);
}
__device__ __forceinline__ float ldf(const void* p, int i, int isbf) {
    return isbf ? bf_to_f(((const unsigned short*)p)[i]) : ((const float*)p)[i];
}
__device__ __forceinline__ int lde(const int* p, int i, int is64) {
    return is64 ? p[2 * i] : p[i];
}

// in-kernel dtype sniff: wave 0 ballots, result broadcast via LDS.
__device__ __forceinline__ int sniff_isbf(const void* W1, int t, int* sh) {
    if (t < 64) {
        unsigned int wv = ((const unsigned int*)W1)[t];
        unsigned int ax = wv & 0x7FFFu;
        int pl = (ax == 0u) || (ax > 0x2000u && ax < 0x4000u);
        unsigned long long mk = __ballot(pl);
        if (t == 0) *sh = (__popcll(mk) >= 48) ? 1 : 0;
    }
    __syncthreads();
    return *sh;
}

// ---------- MERGED prep: pack | fuse | w2frag | fused count+reserve+scatter ----------
// gcnt pre-zeroed by hipMemsetAsync. Scatter carries edge rows in registers across the
// hist -> reserve -> scatter phases: ei is read exactly once. 128 blocks -> ~8 edges
// per bucket per block = 32 B slot runs (half the partial-line write amplification).
__global__ void __launch_bounds__(1024) gcn_prep(
        const void* __restrict__ xr, const void* __restrict__ xu, const void* __restrict__ xp,
        const void* __restrict__ Wr, const void* __restrict__ br,
        const void* __restrict__ Wu, const void* __restrict__ bu,
        const void* __restrict__ Wp, const void* __restrict__ bp,
        const void* __restrict__ W1, const void* __restrict__ W2,
        const int* __restrict__ ei,
        unsigned short* __restrict__ fwfrag, unsigned short* __restrict__ w2frag,
        uint4* __restrict__ xpack, int* __restrict__ gcnt,
        unsigned int* __restrict__ slots) {
    __shared__ __align__(16) char smem[29696];
    __shared__ int sflag;
    int t = threadIdx.x;
    int bx = blockIdx.x;
    if (bx < kPackB) {                       // ---- pack (1024 thr) ----
        int isbf = sniff_isbf(W1, t, &sflag);
        int n = bx * 1024 + t;
        if (n >= kN) return;
        const void* base; int roff, d;
        if (n < kNR)            { base = xr; roff = n * 5;               d = 5; }
        else if (n < kNR + kNU) { base = xu; roff = (n - kNR) * 7;       d = 7; }
        else                    { base = xp; roff = (n - kNR - kNU) * 6; d = 6; }
        float f[8];
        #pragma unroll
        for (int i = 0; i < 8; i++) f[i] = (i < d) ? ldf(base, roff + i, isbf) : 0.f;
        uint4 u;
        u.x = pack_bf2(f[0], f[1]);  u.y = pack_bf2(f[2], f[3]);
        u.z = pack_bf2(f[4], f[5]);  u.w = pack_bf2(f[6], f[7]);
        xpack[n] = u;
    } else if (bx == kFuseB) {               // ---- fuse -> fwfrag (split-k, 256 active) ----
        int isbf = sniff_isbf(W1, t, &sflag);
        float* sw   = (float*)smem;                          // 21*128 f32 = 10752 B
        float* pacc = (float*)(smem + 10752);                // 10752 B
        unsigned short* flds = (unsigned short*)(smem + 21504);  // 8192 B
        for (int i = t; i < 21 * kF; i += 1024) {
            int r = i >> 7, c = i & 127;
            float v;
            if (r < 5)        v = ldf(Wr, r * kF + c, isbf);
            else if (r < 12)  v = ldf(Wu, (r - 5) * kF + c, isbf);
            else if (r < 18)  v = ldf(Wp, (r - 12) * kF + c, isbf);
            else if (r == 18) v = ldf(br, c, isbf);
            else if (r == 19) v = ldf(bu, c, isbf);
            else              v = ldf(bp, c, isbf);
            sw[i] = v;
        }
        __syncthreads();
        {
            bool active = (t < 256);
            int j = t & 127, half = (t >> 7) & 1;
            float acc[21];
            #pragma unroll
            for (int r = 0; r < 21; r++) acc[r] = 0.f;
            if (active) {
                int k0 = half * 64, k1 = k0 + 64;
                for (int k = k0; k < k1; k++) {
                    float w1 = ldf(W1, k * kF + j, isbf);
                    #pragma unroll
                    for (int r = 0; r < 21; r++) acc[r] += sw[r * kF + k] * w1;
                }
            }
            if (active && half == 1) {
                #pragma unroll
                for (int r = 0; r < 21; r++) pacc[r * kF + j] = acc[r];
            }
            __syncthreads();
            if (active && half == 0) {
                #pragma unroll
                for (int r = 0; r < 21; r++) acc[r] += pacc[r * kF + j];
                unsigned short row[32];
                #pragma unroll
                for (int s = 0; s < 32; s++) row[s] = 0;
                #pragma unroll
                for (int i = 0; i < 5; i++) row[0  + i] = f_to_bf(acc[i]);
                #pragma unroll
                for (int i = 0; i < 7; i++) row[8  + i] = f_to_bf(acc[5 + i]);
                #pragma unroll
                for (int i = 0; i < 6; i++) row[16 + i] = f_to_bf(acc[12 + i]);
                row[24] = f_to_bf(acc[18]);  row[25] = f_to_bf(acc[19]);  row[26] = f_to_bf(acc[20]);
                #pragma unroll
                for (int s = 0; s < 32; s++) flds[j * 32 + s] = row[s];
            }
        }
        __syncthreads();
        for (int idx = t; idx < 8 * 64; idx += 1024) {
            int t8 = idx >> 6, lane = idx & 63;
            int mm = lane & 15, q = lane >> 4;
            #pragma unroll
            for (int j = 0; j < 8; j++)
                fwfrag[idx * 8 + j] = flds[(16 * t8 + mm) * 32 + q * 8 + j];
        }
    } else if (bx == kW2B) {                 // ---- W2 -> w2frag ----
        int isbf = sniff_isbf(W1, t, &sflag);
        for (int idx = t; idx < 12 * 64; idx += 1024) {
            int st = idx >> 6, lane = idx & 63;
            int s = st / 3, tt = st % 3;
            int mm = lane & 15, q = lane >> 4;
            int cls = 16 * tt + mm;
            #pragma unroll
            for (int j = 0; j < 8; j++) {
                int k = s * 32 + q * 8 + j;
                w2frag[idx * 8 + j] = (cls < kC) ? f_to_bf(ldf(W2, k * kC + cls, isbf))
                                                 : (unsigned short)0;
            }
        }
    } else {                                 // ---- scatter (128 blocks x 12500 edges) ----
        int* hist = (int*)smem;              // 6400 B
        int* cur  = (int*)(smem + 6400);     // 6400 B
        if (t < 64) {
            int v = ((const int*)ei)[2 * t + 1];
            unsigned long long mk = __ballot(v != 0);
            if (t == 0) sflag = (mk == 0ull) ? 1 : 0;
        }
        for (int i = t; i < kNBp; i += 1024) hist[i] = 0;
        __syncthreads();
        int is64 = sflag;
        int blk = bx - kScat0;
        int e0 = blk * kCE, e1 = e0 + kCE;
        // single read of both edge rows -> registers
        unsigned int dv[kEPT], sv[kEPT];
        #pragma unroll
        for (int it = 0; it < kEPT; it++) {
            int e = e0 + t + it * 1024;
            bool ok = (e < e1);
            dv[it] = ok ? (unsigned int)lde(ei, kE + e, is64) : 0xFFFFFFFFu;
            sv[it] = ok ? (unsigned int)lde(ei, e, is64) : 0u;
        }
        // pass 1: per-bucket histogram
        #pragma unroll
        for (int it = 0; it < kEPT; it++)
            if (dv[it] < (unsigned int)kN) atomicAdd(&hist[dv[it] >> 6], 1);
        __syncthreads();
        // pass 2: reserve ranges (rotated start to spread same-address contention)
        int off = (blk * 401) % kNBp;
        for (int j = t; j < kNBp; j += 1024) {
            int i = j + off;
            if (i >= kNBp) i -= kNBp;
            int h = hist[i];
            cur[i] = (h > 0) ? atomicAdd(&gcnt[i], h) : 0;
        }
        __syncthreads();
        // pass 3: scatter pairs from registers
        #pragma unroll
        for (int it = 0; it < kEPT; it++) {
            if (dv[it] < (unsigned int)kN) {
                unsigned int sval = (sv[it] < (unsigned int)kN) ? sv[it] : 0u;
                int b = (int)(dv[it] >> 6);
                int pos = atomicAdd(&cur[b], 1);
                if (pos < kSlot) slots[(size_t)b * kSlot + pos] = (sval << 6) | (dv[it] & 63u);
            }
        }
    }
}

// ---------- MEGA bucket kernel (256 thr): CSR build + layer-1 agg (4 lanes/node) + MFMA ----------
__global__ void __launch_bounds__(256) GCN_2190433321521_kernel(
        const unsigned int* __restrict__ slots,
        const int* __restrict__ gcnt,
        const uint4* __restrict__ xpack,
        const unsigned short* __restrict__ fwfrag,
        const unsigned short* __restrict__ w2frag,
        int* __restrict__ rpb,
        int* __restrict__ rpe,
        int* __restrict__ col,
        unsigned short* __restrict__ hw) {
    __shared__ __align__(16) char smem[25600];
    float*          agg_l  = (float*)smem;                       // [64][29] fp32, 7424 B
    int*            cnt_l  = (int*)(smem + 7424);                // [64] working cursors
    int*            strt_l = (int*)(smem + 7680);                // [64] start cursors
    int*            cntv_l = (int*)(smem + 7936);                // [64] node counts
    unsigned int*   wst    = (unsigned int*)(smem + 8192);       // pair stash [2048], 8 KB
    int*            col_l  = (int*)(smem + 16384);               // col staging [2048], 8 KB
    unsigned short* hbuf   = (unsigned short*)(smem + 8192);     // [4][16][136] (aliases wst+col_l)
    unsigned short* cst    = (unsigned short*)smem;              // c2 stage [64][40] (aliases agg_l)

    int b = blockIdx.x;
    int base = b * kBN;
    int nn = min(kBN, kN - base);
    int tid = threadIdx.x;

    if (tid < kBN) cnt_l[tid] = 0;
    __syncthreads();
    int p0 = b * kSlot;
    int m = min(gcnt[b], kSlot);
    int p1 = p0 + m;

    // pass 1: load pairs once -> stash + per-node histogram
    for (int ib = p0 + tid; ib < p1; ib += 1024) {
        unsigned int w[4]; int ok[4];
        #pragma unroll
        for (int j = 0; j < 4; j++) {
            int i = ib + j * 256;
            ok[j] = (i < p1);
            w[j] = ok[j] ? slots[i] : 0u;
        }
        #pragma unroll
        for (int j = 0; j < 4; j++) {
            int i = ib + j * 256;
            if (ok[j]) {
                wst[i - p0] = w[j];
                atomicAdd(&cnt_l[w[j] & 63u], 1);
            }
        }
    }
    __syncthreads();
    // wave-0 shfl scan over the 64 node-counts
    if (tid < 64) {
        int v = cnt_l[tid];
        int incl = v;
        #pragma unroll
        for (int o = 1; o < 64; o <<= 1) {
            int y = __shfl_up(incl, o, 64);
            if (tid >= o) incl += y;
        }
        int cursor = p0 + incl - v;
        cnt_l[tid]  = cursor;
        strt_l[tid] = cursor;
        cntv_l[tid] = v;
        if (tid < nn) { rpb[base + tid] = cursor; rpe[base + tid] = cursor + v; }
    }
    __syncthreads();

    // pass 2a: col build only (1 LDS atomic per edge)
    for (int i = p0 + tid; i < p1; i += 256) {
        unsigned int w = wst[i - p0];
        unsigned int s = w >> 6;
        int dloc = (int)(w & 63u);
        int pos = atomicAdd(&cnt_l[dloc], 1);
        col_l[pos - p0] = (int)s;
    }
    __syncthreads();
    for (int i = tid; i < m; i += 256) col[p0 + i] = col_l[i];

    // pass 2b: 4 threads per node; register accumulation of 27 slots
    {
        int node = tid >> 2, j = tid & 3;
        float aR[8], aU[8], aP[8];
        #pragma unroll
        for (int i = 0; i < 8; i++) { aR[i] = 0.f; aU[i] = 0.f; aP[i] = 0.f; }
        float cR = 0.f, cU = 0.f, cP = 0.f;
        int start = strt_l[node] - p0;
        int c = cntv_l[node];
        for (int i = start + j; i < start + c; i += 4) {
            int s = col_l[i];
            uint4 u = xpack[s];
            float2 q0 = bf2_to_f2(u.x), q1 = bf2_to_f2(u.y);
            float2 q2 = bf2_to_f2(u.z), q3 = bf2_to_f2(u.w);
            if (s < kNR) {
                aR[0]+=q0.x; aR[1]+=q0.y; aR[2]+=q1.x; aR[3]+=q1.y;
                aR[4]+=q2.x; aR[5]+=q2.y; aR[6]+=q3.x; aR[7]+=q3.y; cR += 1.f;
            } else if (s < kNR + kNU) {
                aU[0]+=q0.x; aU[1]+=q0.y; aU[2]+=q1.x; aU[3]+=q1.y;
                aU[4]+=q2.x; aU[5]+=q2.y; aU[6]+=q3.x; aU[7]+=q3.y; cU += 1.f;
            } else {
                aP[0]+=q0.x; aP[1]+=q0.y; aP[2]+=q1.x; aP[3]+=q1.y;
                aP[4]+=q2.x; aP[5]+=q2.y; aP[6]+=q3.x; aP[7]+=q3.y; cP += 1.f;
            }
        }
        #pragma unroll
        for (int i2 = 0; i2 < 8; i2++) {
            float v = aR[i2];
            v += __shfl_xor(v, 1, 64);  v += __shfl_xor(v, 2, 64);
            if (j == 0) agg_l[node * 29 + i2] = v;
        }
        #pragma unroll
        for (int i2 = 0; i2 < 8; i2++) {
            float v = aU[i2];
            v += __shfl_xor(v, 1, 64);  v += __shfl_xor(v, 2, 64);
            if (j == 0) agg_l[node * 29 + 8 + i2] = v;
        }
        #pragma unroll
        for (int i2 = 0; i2 < 8; i2++) {
            float v = aP[i2];
            v += __shfl_xor(v, 1, 64);  v += __shfl_xor(v, 2, 64);
            if (j == 0) agg_l[node * 29 + 16 + i2] = v;
        }
        float v = cR;
        v += __shfl_xor(v, 1, 64);  v += __shfl_xor(v, 2, 64);
        if (j == 0) agg_l[node * 29 + 24] = v;
        v = cU;
        v += __shfl_xor(v, 1, 64);  v += __shfl_xor(v, 2, 64);
        if (j == 0) agg_l[node * 29 + 25] = v;
        v = cP;
        v += __shfl_xor(v, 1, 64);  v += __shfl_xor(v, 2, 64);
        if (j == 0) agg_l[node * 29 + 26] = v;
    }
    __syncthreads();   // agg_l complete; wst/col_l dead -> hbuf region live

    // ---- fused dense (MFMA): each wave = one 16-node tile; B-frags from global ----
    int wid = tid >> 6, lane = tid & 63;
    int mm = lane & 15, q = lane >> 4;
    int node = wid * 16 + mm;
    bf16x8 a1;
    #pragma unroll
    for (int j = 0; j < 8; j++) {
        int sl = q * 8 + j;
        a1[j] = (sl < 27) ? (short)f_to_bf(agg_l[node * 29 + sl]) : (short)0;
    }
    __syncthreads();   // agg_l fully consumed; cst (aliasing it) may now be written
    const bf16x8* fwf = (const bf16x8*)fwfrag;
    f32x4 c1[8];
    #pragma unroll
    for (int t = 0; t < 8; t++) {
        f32x4 z = {0.f, 0.f, 0.f, 0.f};
        c1[t] = __builtin_amdgcn_mfma_f32_16x16x32_bf16(a1, fwf[t * 64 + lane], z, 0, 0, 0);
    }
    unsigned short* hb = hbuf + wid * 16 * 136;
    #pragma unroll
    for (int t = 0; t < 8; t++) {
        #pragma unroll
        for (int r = 0; r < 4; r++)
            hb[(q * 4 + r) * 136 + 16 * t + mm] = f_to_bf(fmaxf(c1[t][r], 0.f));
    }
    const bf16x8* w2f = (const bf16x8*)w2frag;
    f32x4 c2[3];
    #pragma unroll
    for (int t = 0; t < 3; t++) { c2[t].x = 0.f; c2[t].y = 0.f; c2[t].z = 0.f; c2[t].w = 0.f; }
    #pragma unroll
    for (int s = 0; s < 4; s++) {
        bf16x8 a2 = *(const bf16x8*)&hb[mm * 136 + s * 32 + q * 8];
        #pragma unroll
        for (int t = 0; t < 3; t++)
            c2[t] = __builtin_amdgcn_mfma_f32_16x16x32_bf16(a2, w2f[(s * 3 + t) * 64 + lane],
                                                            c2[t], 0, 0, 0);
    }
    // stage c2 into LDS, then full-line coalesced store (128 B rows, zero pad)
    #pragma unroll
    for (int t = 0; t < 3; t++) {
        int cls = 16 * t + mm;
        if (cls < kC) {
            #pragma unroll
            for (int r = 0; r < 4; r++)
                cst[(wid * 16 + q * 4 + r) * kC + cls] = f_to_bf(c2[t][r]);
        }
    }
    __syncthreads();
    {
        int tot = nn * (kHS / 2);            // uints per padded row = 32
        const unsigned int* cs32 = (const unsigned int*)cst;
        unsigned int* ho = (unsigned int*)(hw + (size_t)base * kHS);
        for (int i = tid; i < tot; i += 256) {
            int row = i >> 5, c = i & 31;
            ho[i] = (c < kC / 2) ? cs32[row * (kC / 2) + c] : 0u;
        }
    }
}

// ---------- layer-2 gather: wave-per-node, 6 groups x 10 lanes, 4-deep prefetch ----------
// hw rows are 128 B line-aligned: every random gather touches exactly one cache line.
// bijective XCD-chunk swizzle keeps each XCD's rpb/rpe/col stream L2-resident.
__global__ void __launch_bounds__(256) gcn_gather2(const unsigned int* __restrict__ hw32,
                                                   const int* __restrict__ rpb,
                                                   const int* __restrict__ rpe,
                                                   const int* __restrict__ col,
                                                   unsigned int* __restrict__ out,
                                                   const void* __restrict__ W1) {
    __shared__ int sisbf;
    int t = threadIdx.x;
    int isbf = sniff_isbf(W1, t, &sisbf);
    int bid = blockIdx.x;
    int swb = (bid & 7) * kGQ + (bid >> 3);      // XCD-contiguous block mapping
    int w = swb * 4 + (t >> 6);
    if (w >= kN) return;
    int lane = t & 63;
    int grp = lane / 10;          // 0..5 active, lanes 60-63 idle
    int cp  = lane % 10;          // dword-pair index: classes 4*cp .. 4*cp+3
    int beg = rpb[w], end = rpe[w];
    float f0 = 0.f, f1 = 0.f, f2 = 0.f, f3 = 0.f;
    if (grp < 6) {
        const uint2* hp = (const uint2*)hw32;    // row = 16 uint2 (128 B)
        int e = beg + grp;
        // prefetch up to 4 col indices -> 4 independent row gathers (covers degree<=24)
        int c0 = (e      < end) ? col[e]      : -1;
        int c1 = (e + 6  < end) ? col[e + 6]  : -1;
        int c2 = (e + 12 < end) ? col[e + 12] : -1;
        int c3 = (e + 18 < end) ? col[e + 18] : -1;
        if (c0 >= 0) {
            uint2 v = hp[(size_t)c0 * 16 + cp];
            float2 a = bf2_to_f2(v.x), bb = bf2_to_f2(v.y);
            f0 += a.x; f1 += a.y; f2 += bb.x; f3 += bb.y;
        }
        if (c1 >= 0) {
            uint2 v = hp[(size_t)c1 * 16 + cp];
            float2 a = bf2_to_f2(v.x), bb = bf2_to_f2(v.y);
            f0 += a.x; f1 += a.y; f2 += bb.x; f3 += bb.y;
        }
        if (c2 >= 0) {
            uint2 v = hp[(size_t)c2 * 16 + cp];
            float2 a = bf2_to_f2(v.x), bb = bf2_to_f2(v.y);
            f0 += a.x; f1 += a.y; f2 += bb.x; f3 += bb.y;
        }
        if (c3 >= 0) {
            uint2 v = hp[(size_t)c3 * 16 + cp];
            float2 a = bf2_to_f2(v.x), bb = bf2_to_f2(v.y);
            f0 += a.x; f1 += a.y; f2 += bb.x; f3 += bb.y;
        }
        // rare tail (degree > 24 for this group)
        for (e += 24; e < end; e += 6) {
            int s = col[e];
            uint2 v = hp[(size_t)s * 16 + cp];
            float2 a = bf2_to_f2(v.x), bb = bf2_to_f2(v.y);
            f0 += a.x; f1 += a.y; f2 += bb.x; f3 += bb.y;
        }
    }
    f0 += __shfl(f0, lane + 30, 64);
    f1 += __shfl(f1, lane + 30, 64);
    f2 += __shfl(f2, lane + 30, 64);
    f3 += __shfl(f3, lane + 30, 64);
    f0 += __shfl(f0, lane + 10, 64) + __shfl(f0, lane + 20, 64);
    f1 += __shfl(f1, lane + 10, 64) + __shfl(f1, lane + 20, 64);
    f2 += __shfl(f2, lane + 10, 64) + __shfl(f2, lane + 20, 64);
    f3 += __shfl(f3, lane + 10, 64) + __shfl(f3, lane + 20, 64);
    if (lane < 10) {
        if (isbf) {
            out[w * 20 + 2 * lane]     = pack_bf2(f0, f1);
            out[w * 20 + 2 * lane + 1] = pack_bf2(f2, f3);
        } else {
            float* of = (float*)out;
            of[w * 40 + 4 * lane]     = f0;
            of[w * 40 + 4 * lane + 1] = f1;
            of[w * 40 + 4 * lane + 2] = f2;
            of[w * 40 + 4 * lane + 3] = f3;
        }
    }
}

extern "C" void kernel_launch(void* const* d_in, const int* in_sizes, int n_in,
                              void* d_out, int out_size, void* d_ws, size_t ws_size,
                              hipStream_t stream) {
    const void* xr = d_in[0];
    const void* xu = d_in[1];
    const void* xp = d_in[2];
    const int*  ei = (const int*)d_in[3];
    const void* Wr = d_in[4];
    const void* br = d_in[5];
    const void* Wu = d_in[6];
    const void* bu = d_in[7];
    const void* Wp = d_in[8];
    const void* bp = d_in[9];
    const void* W1 = d_in[10];
    const void* W2 = d_in[11];
    (void)in_sizes; (void)n_in; (void)out_size; (void)ws_size;

    char* ws = (char*)d_ws;
    size_t off = 0;
    auto alloc = [&](size_t bytes) -> void* {
        void* p = (void*)(ws + off);
        off = (off + bytes + 255) & ~(size_t)255;
        return p;
    };
    int*            gcnt   = (int*)           alloc((size_t)kNBp * 4);           // 6.4 KB
    unsigned short* fwfrag = (unsigned short*)alloc(8 * 64 * 8 * 2);             // 8 KB
    unsigned short* w2frag = (unsigned short*)alloc(12 * 64 * 8 * 2);            // 12 KB
    uint4*          xpack  = (uint4*)         alloc((size_t)kN * 16);            // 1.6 MB
    unsigned int*   slots  = (unsigned int*)  alloc((size_t)kNB * kSlot * 4);    // 12.8 MB
    int*            col    = (int*)           alloc((size_t)kNB * kSlot * 4);    // 12.8 MB
    int*            rpb    = (int*)           alloc((size_t)kN * 4);             // 0.4 MB
    int*            rpe    = (int*)           alloc((size_t)kN * 4);             // 0.4 MB
    unsigned short* hwb    = (unsigned short*)alloc((size_t)kN * kHS * 2);       // 12.8 MB

    hipMemsetAsync(gcnt, 0, (size_t)kNBp * 4, stream);
    gcn_prep<<<kPrepB, 1024, 0, stream>>>(xr, xu, xp, Wr, br, Wu, bu, Wp, bp, W1, W2,
                                          ei, fwfrag, w2frag, xpack, gcnt, slots);
    GCN_2190433321521_kernel<<<kNB, 256, 0, stream>>>(slots, gcnt, xpack, fwfrag, w2frag,
                                                      rpb, rpe, col, hwb);
    gcn_gather2<<<kGB2, 256, 0, stream>>>((const unsigned int*)hwb, rpb, rpe,
                                          col, (unsigned int*)d_out, W1);
}